// Round 2
// baseline (970.638 us; speedup 1.0000x reference)
//
#include <hip/hip_runtime.h>

#define BLOCK 256
#define ROW_D 16384
#define VPT 16          // float4 per thread = 64 floats
#define CAP0 4096       // compacted candidate-list capacity (words)

// Monotonic bijection: float order == unsigned order of key.
__device__ __forceinline__ unsigned keyOf(float f) {
    unsigned u = __float_as_uint(f);
    return (u & 0x80000000u) ? ~u : (u | 0x80000000u);
}
__device__ __forceinline__ float valOf(unsigned m) {
    unsigned u = (m & 0x80000000u) ? (m & 0x7FFFFFFFu) : ~m;
    return __uint_as_float(u);
}

// Ascending inclusive scan across 256 threads. 2 barriers; wsum reuse is
// protected by the leading barrier.
__device__ __forceinline__ unsigned scanIncl(unsigned v, volatile unsigned* wsum, unsigned t) {
    unsigned lane = t & 63u, wv = t >> 6;
    unsigned s = v;
#pragma unroll
    for (int d = 1; d < 64; d <<= 1) {
        unsigned o = __shfl_up(s, (unsigned)d, 64);
        if (lane >= (unsigned)d) s += o;
    }
    __syncthreads();
    if (lane == 63u) wsum[wv] = s;
    __syncthreads();
    unsigned add = 0;
    for (unsigned w = 0; w < wv; ++w) add += wsum[w];
    return s + add;
}

// Descending (suffix) inclusive scan across 256 threads (thread index = bin).
__device__ __forceinline__ unsigned suffixIncl(unsigned v, volatile unsigned* wsum, unsigned t) {
    unsigned lane = t & 63u, wv = t >> 6;
    unsigned s = v;
#pragma unroll
    for (int d = 1; d < 64; d <<= 1) {
        unsigned o = __shfl_down(s, (unsigned)d, 64);
        if (lane + (unsigned)d < 64u) s += o;
    }
    __syncthreads();
    if (lane == 0u) wsum[wv] = s;
    __syncthreads();
    unsigned add = 0;
    for (unsigned w = wv + 1; w < 4u; ++w) add += wsum[w];
    return s + add;
}

__global__ __launch_bounds__(BLOCK, 4)
void TopKActivation_68324339745162_kernel(const float* __restrict__ in,
                                          float* __restrict__ out,
                                          const int* __restrict__ kptr) {
    // pool layout over time:
    //   pass 0: hist[256 bins][32 copies] = 8192 words (copy in low bits -> bank = copy)
    //   after : list  = pool[0..4095]   (compacted candidates)
    //           hist1 = pool[4096..6143] (256 bins x 8 copies)
    //           list2 = pool[6144..6399] (final <=256 candidates)
    __shared__ unsigned pool[8192];   // 32 KiB
    __shared__ unsigned wsum[4];
    __shared__ unsigned sDig, sGr, sCnt, sT, sNeed, sEq, sBase;

    const unsigned t = threadIdx.x;
    const size_t rowOff = (size_t)blockIdx.x * (size_t)ROW_D;
    const float4* inRow = reinterpret_cast<const float4*>(in + rowOff);
    float4* outRow = reinterpret_cast<float4*>(out + rowOff);

    // ---- Load row once; keys live in registers (64 VGPRs) ----
    uint4 keys[VPT];
#pragma unroll
    for (int j = 0; j < VPT; ++j) {
        float4 v = inRow[t + BLOCK * j];
        keys[j].x = keyOf(v.x);
        keys[j].y = keyOf(v.y);
        keys[j].z = keyOf(v.z);
        keys[j].w = keyOf(v.w);
    }

    unsigned rank = (unsigned)(*kptr);   // k-th largest, 1-based

    // ================= pass 0: digit = bits 24..31, 32 copies =================
    {
        uint4* p4 = reinterpret_cast<uint4*>(pool);
        uint4 z; z.x = z.y = z.z = z.w = 0u;
#pragma unroll
        for (int i = 0; i < 8; ++i) p4[t + 256 * i] = z;
    }
    __syncthreads();
    {
        const unsigned cpy = t & 31u;
#pragma unroll
        for (int j = 0; j < VPT; ++j) {
            atomicAdd(&pool[((keys[j].x >> 24) << 5) | cpy], 1u);
            atomicAdd(&pool[((keys[j].y >> 24) << 5) | cpy], 1u);
            atomicAdd(&pool[((keys[j].z >> 24) << 5) | cpy], 1u);
            atomicAdd(&pool[((keys[j].w >> 24) << 5) | cpy], 1u);
        }
    }
    __syncthreads();
    unsigned c0 = 0;
#pragma unroll
    for (unsigned i = 0; i < 32; ++i) c0 += pool[(t << 5) | ((t + i) & 31u)];  // rotated: bank-clean
    {
        unsigned S = suffixIncl(c0, wsum, t);
        if (S >= rank && S - c0 < rank) { sDig = t; sGr = S - c0; sCnt = c0; }
    }
    __syncthreads();
    unsigned prefix = sDig << 24;
    unsigned pmask  = 0xFF000000u;
    unsigned cnt    = sCnt;
    rank -= sGr;

    // ---- compact pass-0 candidates into LDS list (typ. ~2600 of 16384) ----
    unsigned srcList = 0, listN = 0;
    if (cnt <= CAP0) {
        const unsigned dig0 = prefix >> 24;
        unsigned m = 0;
#pragma unroll
        for (int j = 0; j < VPT; ++j) {
            m += ((keys[j].x >> 24) == dig0);
            m += ((keys[j].y >> 24) == dig0);
            m += ((keys[j].z >> 24) == dig0);
            m += ((keys[j].w >> 24) == dig0);
        }
        unsigned incl = scanIncl(m, wsum, t);   // barriers also fence pass-0 hist reads
        unsigned pos = incl - m;
#pragma unroll
        for (int j = 0; j < VPT; ++j) {
            if ((keys[j].x >> 24) == dig0) pool[pos++] = keys[j].x;
            if ((keys[j].y >> 24) == dig0) pool[pos++] = keys[j].y;
            if ((keys[j].z >> 24) == dig0) pool[pos++] = keys[j].z;
            if ((keys[j].w >> 24) == dig0) pool[pos++] = keys[j].w;
        }
        srcList = 1;
        listN = cnt;
        __syncthreads();
    }

    unsigned* hist1 = pool + 4096;
    unsigned* list2 = pool + 6144;
    unsigned T = 0, need = 0, eqc = 0;
    bool done = false;

    for (int p = 1; p <= 3; ++p) {
        if (cnt <= 256u) {
            // ---- final: exact rank among <=256 candidates (all-pairs) ----
            unsigned m = 0;
            if (srcList) {
                for (unsigned i = t; i < listN; i += BLOCK)
                    m += ((pool[i] & pmask) == prefix);
            } else {
#pragma unroll
                for (int j = 0; j < VPT; ++j) {
                    m += ((keys[j].x & pmask) == prefix);
                    m += ((keys[j].y & pmask) == prefix);
                    m += ((keys[j].z & pmask) == prefix);
                    m += ((keys[j].w & pmask) == prefix);
                }
            }
            unsigned incl = scanIncl(m, wsum, t);
            unsigned pos = incl - m;
            if (srcList) {
                for (unsigned i = t; i < listN; i += BLOCK) {
                    unsigned kk = pool[i];
                    if ((kk & pmask) == prefix) list2[pos++] = kk;
                }
            } else {
#pragma unroll
                for (int j = 0; j < VPT; ++j) {
                    if ((keys[j].x & pmask) == prefix) list2[pos++] = keys[j].x;
                    if ((keys[j].y & pmask) == prefix) list2[pos++] = keys[j].y;
                    if ((keys[j].z & pmask) == prefix) list2[pos++] = keys[j].z;
                    if ((keys[j].w & pmask) == prefix) list2[pos++] = keys[j].w;
                }
            }
            __syncthreads();
            if (t < cnt) {
                unsigned x = list2[t];
                unsigned g = 0, e = 0;
                for (unsigned j = 0; j < cnt; ++j) {
                    unsigned y = list2[j];    // broadcast read, conflict-free
                    g += (y > x);
                    e += (y == x);
                }
                if (g < rank && rank <= g + e) { sT = x; sNeed = rank - g; sEq = e; }
            }
            __syncthreads();
            T = sT; need = sNeed; eqc = sEq;
            done = true;
            break;
        }

        // ---- generic radix pass p over current candidates (8-copy hist) ----
        const int shift = 24 - 8 * p;
        {
            uint4* h4 = reinterpret_cast<uint4*>(hist1);
            uint4 z; z.x = z.y = z.z = z.w = 0u;
            h4[2 * t] = z;
            h4[2 * t + 1] = z;
        }
        __syncthreads();
        const unsigned c8 = t & 7u;
        if (srcList) {
            for (unsigned i = t; i < listN; i += BLOCK) {
                unsigned kk = pool[i];
                if ((kk & pmask) == prefix)
                    atomicAdd(&hist1[(((kk >> shift) & 255u) << 3) | c8], 1u);
            }
        } else {
#pragma unroll
            for (int j = 0; j < VPT; ++j) {
                unsigned kk;
                kk = keys[j].x; if ((kk & pmask) == prefix) atomicAdd(&hist1[(((kk >> shift) & 255u) << 3) | c8], 1u);
                kk = keys[j].y; if ((kk & pmask) == prefix) atomicAdd(&hist1[(((kk >> shift) & 255u) << 3) | c8], 1u);
                kk = keys[j].z; if ((kk & pmask) == prefix) atomicAdd(&hist1[(((kk >> shift) & 255u) << 3) | c8], 1u);
                kk = keys[j].w; if ((kk & pmask) == prefix) atomicAdd(&hist1[(((kk >> shift) & 255u) << 3) | c8], 1u);
            }
        }
        __syncthreads();
        unsigned c = 0;
#pragma unroll
        for (unsigned i = 0; i < 8; ++i) c += hist1[(t << 3) | ((t + i) & 7u)];
        unsigned S = suffixIncl(c, wsum, t);
        if (S >= rank && S - c < rank) { sDig = t; sGr = S - c; sCnt = c; }
        __syncthreads();
        prefix |= (sDig << shift);
        pmask  |= (255u << shift);
        cnt = sCnt;
        rank -= sGr;
    }
    if (!done) { T = prefix; need = rank; eqc = cnt; }   // fully resolved by 4 passes

    // ================= write phase =================
    const bool fastTies = (eqc == need);   // block-uniform
    if (fastTies) {
#pragma unroll
        for (int j = 0; j < VPT; ++j) {
            float4 o;
            o.x = (keys[j].x >= T) ? valOf(keys[j].x) : 0.0f;
            o.y = (keys[j].y >= T) ? valOf(keys[j].y) : 0.0f;
            o.z = (keys[j].z >= T) ? valOf(keys[j].z) : 0.0f;
            o.w = (keys[j].w >= T) ? valOf(keys[j].w) : 0.0f;
            outRow[t + BLOCK * j] = o;
        }
    } else {
        // Cold path: duplicated threshold value; accept the `need` ties with
        // smallest global index (index = 1024*j + 4*t + comp).
        if (t == 0) sBase = 0u;
        __syncthreads();
        for (int j = 0; j < VPT; ++j) {
            unsigned lc = (keys[j].x == T) + (keys[j].y == T) + (keys[j].z == T) + (keys[j].w == T);
            unsigned incl = scanIncl(lc, wsum, t);
            unsigned r = sBase + incl - lc;
            float4 o;
            {
                unsigned kk = keys[j].x;
                if (kk > T) o.x = valOf(kk);
                else if (kk == T) { o.x = (r < need) ? valOf(kk) : 0.0f; ++r; }
                else o.x = 0.0f;
            }
            {
                unsigned kk = keys[j].y;
                if (kk > T) o.y = valOf(kk);
                else if (kk == T) { o.y = (r < need) ? valOf(kk) : 0.0f; ++r; }
                else o.y = 0.0f;
            }
            {
                unsigned kk = keys[j].z;
                if (kk > T) o.z = valOf(kk);
                else if (kk == T) { o.z = (r < need) ? valOf(kk) : 0.0f; ++r; }
                else o.z = 0.0f;
            }
            {
                unsigned kk = keys[j].w;
                if (kk > T) o.w = valOf(kk);
                else if (kk == T) { o.w = (r < need) ? valOf(kk) : 0.0f; ++r; }
                else o.w = 0.0f;
            }
            outRow[t + BLOCK * j] = o;
            __syncthreads();
            if (t == BLOCK - 1) sBase += incl;   // thread 255's incl == total this j
        }
    }
}

extern "C" void kernel_launch(void* const* d_in, const int* in_sizes, int n_in,
                              void* d_out, int out_size, void* d_ws, size_t ws_size,
                              hipStream_t stream) {
    const float* in = (const float*)d_in[0];
    const int* kptr = (const int*)d_in[1];
    float* out = (float*)d_out;
    const int N = in_sizes[0] / ROW_D;   // 8192 rows
    TopKActivation_68324339745162_kernel<<<dim3(N), dim3(BLOCK), 0, stream>>>(in, out, kptr);
}